// Round 4
// baseline (194.575 us; speedup 1.0000x reference)
//
#include <hip/hip_runtime.h>
#include <math.h>

#define HWSZ 784      // 28*28
#define NCH  2048
#define NB   16
#define NWIN 1595     // 625 + 529 + 441
#define NF4  196      // 784/4

// One kernel: grid (nchunks, NB). Phase A: each block sums its channel chunk.
// True last-arriving block per batch (counters zeroed by hipMemsetAsync each
// call) does reduce -> pool -> NMS for that batch.
__global__ __launch_bounds__(256) void k_all(const float* __restrict__ in,
                                             float* __restrict__ part,
                                             unsigned int* __restrict__ cnt,
                                             int cc, int nchunks,
                                             float* __restrict__ out) {
    __shared__ float xs[HWSZ];
    __shared__ float sc[NWIN];
    __shared__ int   winner_s;

    int chunk = blockIdx.x;
    int b     = blockIdx.y;
    int t     = threadIdx.x;

    // ---------- Phase A: partial channel sum for (b, chunk) ----------
    if (t < NF4) {
        const float4* p = reinterpret_cast<const float4*>(
            in + ((size_t)b * NCH + (size_t)chunk * cc) * HWSZ) + t;
        float4 acc = make_float4(0.f, 0.f, 0.f, 0.f);
#pragma unroll 8
        for (int c = 0; c < cc; ++c) {
            float4 v = p[(size_t)c * NF4];
            acc.x += v.x; acc.y += v.y; acc.z += v.z; acc.w += v.w;
        }
        reinterpret_cast<float4*>(part + ((size_t)b * nchunks + chunk) * HWSZ)[t] = acc;
    }

    // ---------- arrival: release stores, count, acquire on winner ----------
    __threadfence();          // release: publish partial stores device-wide
    __syncthreads();
    if (t == 0) {
        unsigned int old = __hip_atomic_fetch_add(&cnt[b], 1u,
                                                  __ATOMIC_ACQ_REL,
                                                  __HIP_MEMORY_SCOPE_AGENT);
        winner_s = (old == (unsigned)(nchunks - 1));   // counters zeroed per call
    }
    __syncthreads();
    if (!winner_s) return;
    __threadfence();          // acquire: invalidate caches, see all partials

    // ---------- Phase B: reduce partials -> xs ----------
    if (t < NF4) {
        float4 acc = make_float4(0.f, 0.f, 0.f, 0.f);
#pragma unroll 8
        for (int ch = 0; ch < nchunks; ++ch) {
            float4 v = reinterpret_cast<const float4*>(
                part + ((size_t)b * nchunks + ch) * HWSZ)[t];
            acc.x += v.x; acc.y += v.y; acc.z += v.z; acc.w += v.w;
        }
        reinterpret_cast<float4*>(xs)[t] = acc;
    }
    __syncthreads();

    // ---------- pool -> sc (LDS) + window_scores (global) ----------
    float* out_win = out + 192;
    for (int w = t; w < NWIN; w += 256) {
        int k, n, base;
        if (w < 625)       { k = 4; n = 25; base = 0;    }
        else if (w < 1154) { k = 6; n = 23; base = 625;  }
        else               { k = 8; n = 21; base = 1154; }
        int loc = w - base;
        int i = loc / n, j = loc % n;
        float s = 0.f;
        for (int di = 0; di < k; ++di) {
            const float* row = xs + (i + di) * 28 + j;
            for (int dj = 0; dj < k; ++dj) s += row[dj];
        }
        s /= (float)(k * k);
        sc[w] = s;
        out_win[(size_t)b * NWIN + w] = s;
    }
    __syncthreads();

    // ---------- NMS: wave g handles group g, in registers ----------
    int wave = t >> 6, lane = t & 63;
    if (wave < 3) {
        const int kArr[3]    = {4, 6, 8};
        const int nArr[3]    = {25, 23, 21};
        const int baseArr[3] = {0, 625, 1154};
        const int pickArr[3] = {3, 2, 1};
        const int offArr[3]  = {0, 3, 5};
        int k = kArr[wave], n = nArr[wave], base = baseArr[wave];
        int npick = pickArr[wave], off = offArr[wave];
        int cnt_w = n * n;          // <= 625 -> <= 10 slots/lane
        int kk2 = 2 * k * k;

        float s[10];
#pragma unroll
        for (int j = 0; j < 10; ++j) {
            int w = lane + 64 * j;
            s[j] = (w < cnt_w) ? sc[base + w] : -INFINITY;
        }

        for (int r = 0; r < npick; ++r) {
            float bs = -INFINITY;
            int   bi = 1 << 30;
#pragma unroll
            for (int j = 0; j < 10; ++j) {
                int w = lane + 64 * j;
                float v = s[j];
                if (v > bs || (v == bs && w < bi)) { bs = v; bi = w; }
            }
#pragma unroll
            for (int m = 1; m < 64; m <<= 1) {
                float os = __shfl_xor(bs, m);
                int   oi = __shfl_xor(bi, m);
                if (os > bs || (os == bs && oi < bi)) { bs = os; bi = oi; }
            }
            if (lane == 0) {
                out[(size_t)b * 6 + off + r]      = (float)(base + bi);
                out[96 + (size_t)b * 6 + off + r] = bs;
            }
            int pi = bi / n, pj = bi % n;
#pragma unroll
            for (int j = 0; j < 10; ++j) {
                int w = lane + 64 * j;
                int i  = w / n, jj = w % n;
                int di = i - pi;  if (di < 0) di = -di;
                int dj = jj - pj; if (dj < 0) dj = -dj;
                int iw = k - dj, ih = k - di;
                int inter = (iw > 0 && ih > 0) ? iw * ih : 0;
                if (5 * inter > kk2) s[j] = -INFINITY;
            }
        }
    }
}

extern "C" void kernel_launch(void* const* d_in, const int* in_sizes, int n_in,
                              void* d_out, int out_size, void* d_ws, size_t ws_size,
                              hipStream_t stream) {
    // input order: num_proposals, input_tensor, window_nums_sum, N_list, iou_thresholds, coordinates_cat
    const float* in = (const float*)d_in[1];
    float* out = (float*)d_out;
    float* ws  = (float*)d_ws;

    // ws layout: [0..63] floats reserved (first 16 uints = arrival counters), then partials
    unsigned int* cnt = (unsigned int*)ws;
    float* part = ws + 64;

    size_t ws_floats = ws_size / 4;
    int nchunks = 64;
    while (nchunks > 1 && 64 + (size_t)NB * nchunks * HWSZ > ws_floats) nchunks >>= 1;
    int cc = NCH / nchunks;

    // zero the arrival counters every call (async memset is graph-capturable)
    hipMemsetAsync(cnt, 0, NB * sizeof(unsigned int), stream);

    dim3 g(nchunks, NB);
    k_all<<<g, 256, 0, stream>>>(in, part, cnt, cc, nchunks, out);
}

// Round 5
// 39.188 us; speedup vs baseline: 4.9652x; 4.9652x over previous
//
#include <hip/hip_runtime.h>
#include <math.h>

#define HWSZ   784    // 28*28
#define NCH    2048
#define NB     16
#define NWIN   1595   // 625 + 529 + 441
#define NF4    196    // 784/4
#define NCHUNK 32
#define CC     64     // 2048/32

// ---------------- Kernel 1: per-chunk channel sums ----------------
__global__ __launch_bounds__(256) void k_chan_partial(const float* __restrict__ in,
                                                      float* __restrict__ partial) {
    int chunk = blockIdx.x;
    int b     = blockIdx.y;
    int t     = threadIdx.x;
    if (t >= NF4) return;
    const float4* p = reinterpret_cast<const float4*>(
        in + ((size_t)b * NCH + (size_t)chunk * CC) * HWSZ) + t;
    float4 acc = make_float4(0.f, 0.f, 0.f, 0.f);
#pragma unroll 16
    for (int c = 0; c < CC; ++c) {
        float4 v = p[(size_t)c * NF4];
        acc.x += v.x; acc.y += v.y; acc.z += v.z; acc.w += v.w;
    }
    reinterpret_cast<float4*>(partial + ((size_t)b * NCHUNK + chunk) * HWSZ)[t] = acc;
}

// ---------------- Kernel 2: fused reduce + pool + NMS (one block per batch) ----------------
__global__ __launch_bounds__(256) void k_fused(const float* __restrict__ partial,
                                               float* __restrict__ out) {
    __shared__ float xs[HWSZ];
    __shared__ float sc[NWIN];
    int b = blockIdx.x;
    int t = threadIdx.x;

    // --- reduce partials -> xs ---
    if (t < NF4) {
        float4 acc = make_float4(0.f, 0.f, 0.f, 0.f);
#pragma unroll 16
        for (int ch = 0; ch < NCHUNK; ++ch) {
            float4 v = reinterpret_cast<const float4*>(
                partial + ((size_t)b * NCHUNK + ch) * HWSZ)[t];
            acc.x += v.x; acc.y += v.y; acc.z += v.z; acc.w += v.w;
        }
        reinterpret_cast<float4*>(xs)[t] = acc;
    }
    __syncthreads();

    // --- pool -> sc (LDS) + window_scores (global) ---
    float* out_win = out + 192;
    for (int w = t; w < NWIN; w += 256) {
        int k, n, base;
        if (w < 625)       { k = 4; n = 25; base = 0;    }
        else if (w < 1154) { k = 6; n = 23; base = 625;  }
        else               { k = 8; n = 21; base = 1154; }
        int loc = w - base;
        int i = loc / n, j = loc % n;
        float s = 0.f;
        for (int di = 0; di < k; ++di) {
            const float* row = xs + (i + di) * 28 + j;
            for (int dj = 0; dj < k; ++dj) s += row[dj];
        }
        s /= (float)(k * k);
        sc[w] = s;
        out_win[(size_t)b * NWIN + w] = s;
    }
    __syncthreads();

    // --- NMS: wave g handles group g, entirely in registers ---
    int wave = t >> 6, lane = t & 63;
    if (wave < 3) {
        const int kArr[3]    = {4, 6, 8};
        const int nArr[3]    = {25, 23, 21};
        const int baseArr[3] = {0, 625, 1154};
        const int pickArr[3] = {3, 2, 1};
        const int offArr[3]  = {0, 3, 5};
        int k = kArr[wave], n = nArr[wave], base = baseArr[wave];
        int npick = pickArr[wave], off = offArr[wave];
        int cnt = n * n;           // <= 625 -> <= 10 slots/lane
        int kk2 = 2 * k * k;

        float s[10];
#pragma unroll
        for (int j = 0; j < 10; ++j) {
            int w = lane + 64 * j;
            s[j] = (w < cnt) ? sc[base + w] : -INFINITY;
        }

        for (int r = 0; r < npick; ++r) {
            // lane-local argmax (max score, tie -> smallest window index)
            float bs = -INFINITY;
            int   bi = 1 << 30;
#pragma unroll
            for (int j = 0; j < 10; ++j) {
                int w = lane + 64 * j;
                float v = s[j];
                if (v > bs || (v == bs && w < bi)) { bs = v; bi = w; }
            }
            // wave butterfly reduce
#pragma unroll
            for (int m = 1; m < 64; m <<= 1) {
                float os = __shfl_xor(bs, m);
                int   oi = __shfl_xor(bi, m);
                if (os > bs || (os == bs && oi < bi)) { bs = os; bi = oi; }
            }
            if (lane == 0) {
                out[(size_t)b * 6 + off + r]      = (float)(base + bi);
                out[96 + (size_t)b * 6 + off + r] = bs;
            }
            // suppress: IoU > 0.25  <=>  5*inter > 2*k*k (same-size boxes, exact int test)
            int pi = bi / n, pj = bi % n;
#pragma unroll
            for (int j = 0; j < 10; ++j) {
                int w = lane + 64 * j;
                int i  = w / n, jj = w % n;
                int di = i - pi;  if (di < 0) di = -di;
                int dj = jj - pj; if (dj < 0) dj = -dj;
                int iw = k - dj, ih = k - di;
                int inter = (iw > 0 && ih > 0) ? iw * ih : 0;
                if (5 * inter > kk2) s[j] = -INFINITY;
            }
        }
    }
}

extern "C" void kernel_launch(void* const* d_in, const int* in_sizes, int n_in,
                              void* d_out, int out_size, void* d_ws, size_t ws_size,
                              hipStream_t stream) {
    // input order: num_proposals, input_tensor, window_nums_sum, N_list, iou_thresholds, coordinates_cat
    const float* in = (const float*)d_in[1];
    float* out = (float*)d_out;
    float* part = (float*)d_ws;   // 16*32*784 floats = 1.6 MB

    dim3 g1(NCHUNK, NB);
    k_chan_partial<<<g1, 256, 0, stream>>>(in, part);
    k_fused<<<NB, 256, 0, stream>>>(part, out);
}

// Round 6
// 29.025 us; speedup vs baseline: 6.7036x; 1.3501x over previous
//
#include <hip/hip_runtime.h>
#include <math.h>

#define HWSZ   784    // 28*28
#define NCH    2048
#define NB     16
#define NWIN   1595   // 625 + 529 + 441
#define NF4    196    // 784/4
#define NCHUNK 32
#define CC     64     // 2048/32

// ---------------- Kernel 1: per-chunk channel sums (unchanged, proven) ----------------
__global__ __launch_bounds__(256) void k_chan_partial(const float* __restrict__ in,
                                                      float* __restrict__ partial) {
    int chunk = blockIdx.x;
    int b     = blockIdx.y;
    int t     = threadIdx.x;
    if (t >= NF4) return;
    const float4* p = reinterpret_cast<const float4*>(
        in + ((size_t)b * NCH + (size_t)chunk * CC) * HWSZ) + t;
    float4 acc = make_float4(0.f, 0.f, 0.f, 0.f);
#pragma unroll 16
    for (int c = 0; c < CC; ++c) {
        float4 v = p[(size_t)c * NF4];
        acc.x += v.x; acc.y += v.y; acc.z += v.z; acc.w += v.w;
    }
    reinterpret_cast<float4*>(partial + ((size_t)b * NCHUNK + chunk) * HWSZ)[t] = acc;
}

// ---------------- Kernel 2: per-(group,batch) reduce + separable pool + NMS ----------------
// grid (3, NB); each block re-reduces partials (L2-hit) then handles only its group.
__global__ __launch_bounds__(256) void k_fused(const float* __restrict__ partial,
                                               float* __restrict__ out) {
    __shared__ float xs[HWSZ];
    __shared__ float rowsum[28 * 25];   // 28 rows x n cols (n<=25)
    __shared__ float sc[625];
    int g = blockIdx.x;
    int b = blockIdx.y;
    int t = threadIdx.x;

    const int kArr[3]    = {4, 6, 8};
    const int nArr[3]    = {25, 23, 21};
    const int baseArr[3] = {0, 625, 1154};
    const int pickArr[3] = {3, 2, 1};
    const int offArr[3]  = {0, 3, 5};
    int k = kArr[g], n = nArr[g], base = baseArr[g];
    int cnt = n * n;

    // --- reduce partials -> xs (redundant per group; 100KB L2/L3 reads) ---
    if (t < NF4) {
        float4 acc = make_float4(0.f, 0.f, 0.f, 0.f);
#pragma unroll 16
        for (int ch = 0; ch < NCHUNK; ++ch) {
            float4 v = reinterpret_cast<const float4*>(
                partial + ((size_t)b * NCHUNK + ch) * HWSZ)[t];
            acc.x += v.x; acc.y += v.y; acc.z += v.z; acc.w += v.w;
        }
        reinterpret_cast<float4*>(xs)[t] = acc;
    }
    __syncthreads();

    // --- per-row sliding sums: rowsum[row*n + j] = sum_{dj<k} xs[row*28 + j+dj] ---
    int nrs = 28 * n;
    for (int idx = t; idx < nrs; idx += 256) {
        int row = idx / n, j = idx % n;
        const float* xr = xs + row * 28 + j;
        float s = 0.f;
        for (int dj = 0; dj < k; ++dj) s += xr[dj];
        rowsum[idx] = s;
    }
    __syncthreads();

    // --- windows: k adds of rowsums; write LDS copy + global window_scores ---
    float* out_win = out + 192;
    float inv = 1.f / (float)(k * k);
    for (int w = t; w < cnt; w += 256) {
        int i = w / n, j = w % n;
        const float* rp = rowsum + i * n + j;
        float s = 0.f;
        for (int di = 0; di < k; ++di) s += rp[di * n];
        s *= inv;
        sc[w] = s;
        out_win[(size_t)b * NWIN + base + w] = s;
    }
    __syncthreads();

    // --- NMS: wave 0, fully in registers ---
    if (t < 64) {
        int lane = t;
        int npick = pickArr[g], off = offArr[g];
        int kk2 = 2 * k * k;

        float s[10];
#pragma unroll
        for (int j = 0; j < 10; ++j) {
            int w = lane + 64 * j;
            s[j] = (w < cnt) ? sc[w] : -INFINITY;
        }

        for (int r = 0; r < npick; ++r) {
            // lane-local argmax (max score, tie -> smallest window index)
            float bs = -INFINITY;
            int   bi = 1 << 30;
#pragma unroll
            for (int j = 0; j < 10; ++j) {
                int w = lane + 64 * j;
                float v = s[j];
                if (v > bs || (v == bs && w < bi)) { bs = v; bi = w; }
            }
            // wave butterfly reduce
#pragma unroll
            for (int m = 1; m < 64; m <<= 1) {
                float os = __shfl_xor(bs, m);
                int   oi = __shfl_xor(bi, m);
                if (os > bs || (os == bs && oi < bi)) { bs = os; bi = oi; }
            }
            if (lane == 0) {
                out[(size_t)b * 6 + off + r]      = (float)(base + bi);
                out[96 + (size_t)b * 6 + off + r] = bs;
            }
            // suppress: IoU > 0.25  <=>  5*inter > 2*k*k (same-size boxes, exact int test)
            int pi = bi / n, pj = bi % n;
#pragma unroll
            for (int j = 0; j < 10; ++j) {
                int w = lane + 64 * j;
                int i  = w / n, jj = w % n;
                int di = i - pi;  if (di < 0) di = -di;
                int dj = jj - pj; if (dj < 0) dj = -dj;
                int iw = k - dj, ih = k - di;
                int inter = (iw > 0 && ih > 0) ? iw * ih : 0;
                if (5 * inter > kk2) s[j] = -INFINITY;
            }
        }
    }
}

extern "C" void kernel_launch(void* const* d_in, const int* in_sizes, int n_in,
                              void* d_out, int out_size, void* d_ws, size_t ws_size,
                              hipStream_t stream) {
    // input order: num_proposals, input_tensor, window_nums_sum, N_list, iou_thresholds, coordinates_cat
    const float* in = (const float*)d_in[1];
    float* out = (float*)d_out;
    float* part = (float*)d_ws;   // 16*32*784 floats = 1.6 MB

    dim3 g1(NCHUNK, NB);
    k_chan_partial<<<g1, 256, 0, stream>>>(in, part);
    dim3 g2(3, NB);
    k_fused<<<g2, 256, 0, stream>>>(part, out);
}